// Round 5
// baseline (329.524 us; speedup 1.0000x reference)
//
#include <hip/hip_runtime.h>

typedef _Float16 f16;
typedef __attribute__((ext_vector_type(2))) _Float16 f16v2;
typedef __attribute__((ext_vector_type(8))) _Float16 f16x8;
typedef __attribute__((ext_vector_type(2))) __fp16 hf16x2;   // native type of cvt_pkrtz
typedef __attribute__((ext_vector_type(4))) float f32x4;

constexpr int C_ = 4, L_ = 1000, K_ = 64, NOUT = 986, NPOS = 16 * 986; // 15776
constexpr int MTB  = 128;                       // positions per block
constexpr int NBLK = (NPOS + MTB - 1) / MTB;    // 124
constexpr int AST  = 104;                       // row stride (f16): 208 B, 16B-aligned
constexpr int ACT_EL  = MTB * AST;              // 13312 f16 (single in-place buffer)
constexpr int WBUF_EL = 96 * AST;               // 9984 f16
constexpr size_t SMEM_BYTES = (size_t)(ACT_EL + WBUF_EL) * 2 + 480 * 2 + 64 * 4; // 47808 B -> 3 blocks/CU

// ws: per layer l, per k: WROWS[l] rows x AST cols fp16 W^T (row=out e, col=in d), zero-padded
constexpr size_t WOFF[5]  = {0, 638976, 1277952, 1916928, 2555904};
constexpr int    WROWS[5] = {96, 96, 96, 96, 64};
constexpr int    DIv[5]   = {60, 72, 86, 86, 71};
constexpr int    DOv[5]   = {72, 86, 86, 71, 59};

#define H2(c) (f16v2{(f16)(c), (f16)(c)})

// Packed-fp16 tanh-gelu, division/trans-free.
// gelu(x) ~= x*(0.5 + 0.5*tanh(z)), z = x*(0.79788456 + 0.035677408 x^2), clamp z to [-3.8,3.8].
// tanh(z) = z*Q(z^2); Q approximated by deg-10 poly in s = z^2/7.22 - 1 (Chebyshev fit derived
// analytically from tanh's partial-fraction expansion; |err_Q| <~ 1.6e-4 on the range).
// x==0 -> returns exactly 0 (keeps K-padding columns zero).
__device__ __forceinline__ f16v2 gelu_pk(f16v2 x) {
    f16v2 x2  = x * x;
    f16v2 inr = x2 * H2(0.035677408f) + H2(0.79788456f);
    f16v2 z   = x * inr;
    z = __builtin_elementwise_min(z, H2(3.8f));
    z = __builtin_elementwise_max(z, H2(-3.8f));
    f16v2 w = z * z;
    f16v2 s = w * H2(0.1385042f) + H2(-1.0f);     // s = w/7.22 - 1 in [-1,1]
    f16v2 r = H2(0.1013453f);
    r = r * s + H2(-0.1133210f);
    r = r * s + H2(-0.1266496f);
    r = r * s + H2( 0.1132826f);
    r = r * s + H2( 0.1267140f);
    r = r * s + H2(-0.1204880f);
    r = r * s + H2( 0.0398960f);
    r = r * s + H2(-0.0719470f);
    r = r * s + H2( 0.1213900f);
    r = r * s + H2(-0.1759330f);
    r = r * s + H2( 0.3687210f);                  // r = Q(w)
    f16v2 T = z * r;                              // tanh(z)
    f16v2 S = T * H2(0.5f) + H2(0.5f);
    return x * S;
}

__device__ __forceinline__ f16v2 pack2(float a, float b) {
    hf16x2 h = __builtin_amdgcn_cvt_pkrtz(a, b);
    union { hf16x2 h; f16v2 f; } u; u.h = h; return u.f;
}

__device__ __forceinline__ void async_cp16(const f16* g, f16* l) {
    __builtin_amdgcn_global_load_lds((const __attribute__((address_space(1))) void*)g,
                                     (__attribute__((address_space(3))) void*)l, 16, 0, 0);
}

__device__ __forceinline__ void stage_w(const f16* __restrict__ src, f16* __restrict__ dst,
                                        int chunks, int tid) {
    int wv64 = tid & ~63;   // LDS dest must be wave-uniform base + lane*16
    for (int c0 = 0; c0 < chunks; c0 += 256) {
        int c = c0 + tid;
        if (c < chunks) async_cp16(src + (size_t)c * 8, dst + (size_t)(c0 + wv64) * 8);
    }
}

// A = W^T (m = out-feature e), B = act (n = position). D[m][n] = sum_d W^T[e][d]*act[pos][d].
template<int KSTEPS, int MT>
__device__ __forceinline__ void layer_mm(const f16* __restrict__ actw, const f16* __restrict__ wb,
                                         f32x4 (&acc)[MT][2], int li, int q) {
#pragma unroll
    for (int mt = 0; mt < MT; mt++)
#pragma unroll
        for (int nt = 0; nt < 2; nt++) acc[mt][nt] = f32x4{0.f, 0.f, 0.f, 0.f};
#pragma unroll
    for (int ks = 0; ks < KSTEPS; ks++) {
        const int koff = ks * 32 + q * 8;
        f16x8 a[MT], b[2];
#pragma unroll
        for (int nt = 0; nt < 2; nt++)
            b[nt] = *(const f16x8*)(actw + (nt * 16 + li) * AST + koff);
#pragma unroll
        for (int mt = 0; mt < MT; mt++)
            a[mt] = *(const f16x8*)(wb + (mt * 16 + li) * AST + koff);
#pragma unroll
        for (int mt = 0; mt < MT; mt++)
#pragma unroll
            for (int nt = 0; nt < 2; nt++)
                acc[mt][nt] = __builtin_amdgcn_mfma_f32_16x16x32_f16(a[mt], b[nt], acc[mt][nt], 0, 0, 0);
    }
}

// C/D: col(n=pos)=lane&15, row(m=e)=(lane>>4)*4+r -> lane owns 4 consecutive features of one
// position: bias-add + gelu fully in packed fp16, one ds_write_b64 per (mt,nt).
template<int MT>
__device__ __forceinline__ void epilogue(f32x4 (&acc)[MT][2], f16* __restrict__ actw,
                                         const f16* __restrict__ bh, int li, int q) {
#pragma unroll
    for (int mt = 0; mt < MT; mt++) {
        const int eb = mt * 16 + q * 4;
        f16v2 b01 = *(const f16v2*)(bh + eb);      // same-addr across li: LDS broadcast
        f16v2 b23 = *(const f16v2*)(bh + eb + 2);
#pragma unroll
        for (int nt = 0; nt < 2; nt++) {
            f16v2 g01 = gelu_pk(pack2(acc[mt][nt][0], acc[mt][nt][1]) + b01);
            f16v2 g23 = gelu_pk(pack2(acc[mt][nt][2], acc[mt][nt][3]) + b23);
            f16* dst = actw + (nt * 16 + li) * AST + eb;   // 8B aligned
            union { f16v2 h[2]; unsigned long long u; } pk;
            pk.h[0] = g01; pk.h[1] = g23;
            *(unsigned long long*)dst = pk.u;
        }
    }
}

// prep: fp32 w[k][d][e] -> fp16 W^T[k][e][d], zero-padded
__global__ __launch_bounds__(256) void prep_weights(
    const float* __restrict__ w0, const float* __restrict__ w1, const float* __restrict__ w2,
    const float* __restrict__ w3, const float* __restrict__ w4, f16* __restrict__ ws) {
    __shared__ f16 wl[86 * 86];
    const int k = blockIdx.x, l = blockIdx.y, tid = threadIdx.x;
    const float* wsrc;
    switch (l) { case 0: wsrc = w0; break; case 1: wsrc = w1; break; case 2: wsrc = w2; break;
                 case 3: wsrc = w3; break; default: wsrc = w4; }
    const int DI = DIv[l], DO = DOv[l], RW = WROWS[l];
    wsrc += (size_t)k * DI * DO;
    for (int i = tid; i < DI * DO; i += 256) wl[i] = (f16)wsrc[i];
    __syncthreads();
    f16* dst = ws + WOFF[l] + (size_t)k * RW * AST;
    const int tot = RW * AST;
    for (int i = tid; i < tot; i += 256) {
        int e = i / AST, d = i - e * AST;
        f16 v = (f16)0.f;
        if (e < DO && d < DI) v = wl[d * DO + e];
        dst[i] = v;
    }
}

__global__ __launch_bounds__(256, 3) void mlp_main(
    const float* __restrict__ x,
    const float* __restrict__ b0, const float* __restrict__ b1, const float* __restrict__ b2,
    const float* __restrict__ b3, const float* __restrict__ b4,
    const float* __restrict__ hw, const float* __restrict__ hb,
    const f16* __restrict__ ws, float* __restrict__ out) {
    extern __shared__ char smemraw[];
    f16*   act   = (f16*)smemraw;                 // [128 pos][AST]
    f16*   wbuf  = act + ACT_EL;
    f16*   biash = wbuf + WBUF_EL;                // 5 layers x 96 padded biases, fp16
    float* headl = (float*)(biash + 480);         // 64 padded head weights, fp32

    const int tid = threadIdx.x, k = blockIdx.x, mblk = blockIdx.y;
    const int wv = tid >> 6, lane = tid & 63, li = lane & 15, q = lane >> 4;
    const int base = mblk * MTB;
    f16* actw = act + (wv * 32) * AST;            // this wave's 32 position rows

    stage_w(ws + WOFF[0] + (size_t)k * 96 * AST, wbuf, 96 * AST / 8, tid);  // async W0

    // biases (padded to 96, fp16) + head weights; overlaps with W0 staging
    for (int i = tid; i < 480; i += 256) {
        int l = i / 96, e = i - l * 96;
        const float* bg = (l == 0) ? b0 : (l == 1) ? b1 : (l == 2) ? b2 : (l == 3) ? b3 : b4;
        int DO = (l == 0) ? 72 : (l == 1) ? 86 : (l == 2) ? 86 : (l == 3) ? 71 : 59;
        biash[i] = (f16)((e < DO) ? bg[k * DO + e] : 0.f);
    }
    if (tid < 64) headl[tid] = (tid < 59) ? hw[tid] : 0.f;

    // layer-0 activations: act[pos][d], d = c*15+j in 0..59, cols 60..63 zero (K-pad).
    // b via threshold compare (block spans <=2 batches) instead of per-elem division.
    {
        const int b0i = base / NOUT;
        const int thr = (b0i + 1) * NOUT;
        for (int i = tid; i < 64 * MTB; i += 256) {
            int d = i >> 7, r = i & 127;
            int p = base + r; if (p > NPOS - 1) p = NPOS - 1;
            int b = (p >= thr) ? b0i + 1 : b0i;
            int pos = p - b * NOUT;
            float v = 0.f;
            if (d < 60) { int c = d / 15, j = d - c * 15; v = x[(size_t)(b * C_ + c) * L_ + pos + j]; }
            act[r * AST + d] = (f16)v;
        }
    }
    const float hb0 = hb[0];
    __syncthreads();

    f32x4 acc[6][2];
    layer_mm<2, 6>(actw, wbuf, acc, li, q);              // L0: K=64
    epilogue<6>(acc, actw, biash + 0 * 96, li, q);       // no barrier: act rows wave-private
    __syncthreads();
    stage_w(ws + WOFF[1] + (size_t)k * 96 * AST, wbuf, 96 * AST / 8, tid);
    __syncthreads();
    layer_mm<3, 6>(actw, wbuf, acc, li, q);              // L1: K=96
    epilogue<6>(acc, actw, biash + 1 * 96, li, q);
    __syncthreads();
    stage_w(ws + WOFF[2] + (size_t)k * 96 * AST, wbuf, 96 * AST / 8, tid);
    __syncthreads();
    layer_mm<3, 6>(actw, wbuf, acc, li, q);              // L2
    epilogue<6>(acc, actw, biash + 2 * 96, li, q);
    __syncthreads();
    stage_w(ws + WOFF[3] + (size_t)k * 96 * AST, wbuf, 96 * AST / 8, tid);
    __syncthreads();
    layer_mm<3, 6>(actw, wbuf, acc, li, q);              // L3: e>=71 -> exact 0 (L4 K-pad)
    epilogue<6>(acc, actw, biash + 3 * 96, li, q);
    __syncthreads();
    stage_w(ws + WOFF[4] + (size_t)k * 64 * AST, wbuf, 64 * AST / 8, tid);
    __syncthreads();

    // L4 + fused head: e 0..63 (4 m-tiles), pk gelu then fp32 dot with hw, butterfly over q
    f32x4 acc4[4][2];
    layer_mm<3, 4>(actw, wbuf, acc4, li, q);
    float sum[2] = {0.f, 0.f};
#pragma unroll
    for (int mt = 0; mt < 4; mt++) {
        const int eb = mt * 16 + q * 4;
        f16v2 b01 = *(const f16v2*)(biash + 4 * 96 + eb);
        f16v2 b23 = *(const f16v2*)(biash + 4 * 96 + eb + 2);
        f32x4 hh = *(const f32x4*)(headl + eb);
#pragma unroll
        for (int nt = 0; nt < 2; nt++) {
            f16v2 g01 = gelu_pk(pack2(acc4[mt][nt][0], acc4[mt][nt][1]) + b01);
            f16v2 g23 = gelu_pk(pack2(acc4[mt][nt][2], acc4[mt][nt][3]) + b23);
            sum[nt] += (float)g01[0] * hh[0] + (float)g01[1] * hh[1]
                     + (float)g23[0] * hh[2] + (float)g23[1] * hh[3];
        }
    }
#pragma unroll
    for (int nt = 0; nt < 2; nt++) {
        float s = sum[nt];
        s += __shfl_xor(s, 16);
        s += __shfl_xor(s, 32);
        s += hb0;
        if (lane < 16) {
            int p = base + wv * 32 + nt * 16 + lane;
            if (p < NPOS) {
                int b = p / NOUT, pos = p - b * NOUT;
                out[((size_t)(b * K_ + k)) * NOUT + pos] = s;
            }
        }
    }
}

extern "C" void kernel_launch(void* const* d_in, const int* in_sizes, int n_in,
                              void* d_out, int out_size, void* d_ws, size_t ws_size,
                              hipStream_t stream) {
    const float* x  = (const float*)d_in[0];
    const float* w0 = (const float*)d_in[1];  const float* b0 = (const float*)d_in[2];
    const float* w1 = (const float*)d_in[3];  const float* b1 = (const float*)d_in[4];
    const float* w2 = (const float*)d_in[5];  const float* b2 = (const float*)d_in[6];
    const float* w3 = (const float*)d_in[7];  const float* b3 = (const float*)d_in[8];
    const float* w4 = (const float*)d_in[9];  const float* b4 = (const float*)d_in[10];
    const float* hw = (const float*)d_in[11]; const float* hb = (const float*)d_in[12];
    float* out = (float*)d_out;
    f16* ws = (f16*)d_ws;   // 5.96 MB

    (void)hipFuncSetAttribute((const void*)mlp_main,
                              hipFuncAttributeMaxDynamicSharedMemorySize, (int)SMEM_BYTES);

    prep_weights<<<dim3(K_, 5), 256, 0, stream>>>(w0, w1, w2, w3, w4, ws);
    mlp_main<<<dim3(K_, NBLK), 256, SMEM_BYTES, stream>>>(x, b0, b1, b2, b3, b4, hw, hb, ws, out);
}

// Round 7
// 311.726 us; speedup vs baseline: 1.0571x; 1.0571x over previous
//
#include <hip/hip_runtime.h>

typedef _Float16 f16;
typedef __attribute__((ext_vector_type(2))) _Float16 f16v2;
typedef __attribute__((ext_vector_type(8))) _Float16 f16x8;
typedef __attribute__((ext_vector_type(2))) __fp16 hf16x2;   // native type of cvt_pkrtz
typedef __attribute__((ext_vector_type(4))) float f32x4;

constexpr int C_ = 4, L_ = 1000, K_ = 64, NOUT = 986, NPOS = 16 * 986; // 15776
constexpr int TPB  = 256;                       // 4 waves (R4 config: validated)
constexpr int MTB  = 128;                       // positions per block (32/wave)
constexpr int NBLK = (NPOS + MTB - 1) / MTB;    // 124
constexpr int AST  = 104;                       // row stride (f16): 208 B, 16B-aligned
constexpr int ACT_EL  = MTB * AST;              // 13312 f16 (single in-place buffer)
constexpr int WBUF_EL = 96 * AST;               // 9984 f16
// LDS: act 26624 + wbuf 19968 + bias(fp32) 1920 + head(fp32) 256 = 48768 B -> 3 blocks/CU
constexpr size_t SMEM_BYTES = (size_t)(ACT_EL + WBUF_EL) * 2 + 480 * 4 + 64 * 4;

// ws: per layer l, per k: WROWS[l] rows x AST cols fp16 W^T (row=out e, col=in d), zero-padded
constexpr size_t WOFF[5]  = {0, 638976, 1277952, 1916928, 2555904};
constexpr int    WROWS[5] = {96, 96, 96, 96, 64};
constexpr int    DIv[5]   = {60, 72, 86, 86, 71};
constexpr int    DOv[5]   = {72, 86, 86, 71, 59};

__device__ __forceinline__ float gelu_f(float x) {
    // tanh-form gelu as x*sigmoid(2z); validated R4 (absmax 3.9e-3)
    float x2 = x * x;
    float z  = x * __builtin_fmaf(0.0356774081f, x2, 0.7978845608f);
    float e  = __expf(-2.0f * z);
    return x * __builtin_amdgcn_rcpf(e + 1.0f);
}

__device__ __forceinline__ void async_cp16(const f16* g, f16* l) {
    __builtin_amdgcn_global_load_lds((const __attribute__((address_space(1))) void*)g,
                                     (__attribute__((address_space(3))) void*)l, 16, 0, 0);
}

__device__ __forceinline__ void stage_w(const f16* __restrict__ src, f16* __restrict__ dst,
                                        int chunks, int tid) {
    int wv64 = tid & ~63;   // LDS dest must be wave-uniform base + lane*16
    for (int c0 = 0; c0 < chunks; c0 += TPB) {
        int c = c0 + tid;
        if (c < chunks) async_cp16(src + (size_t)c * 8, dst + (size_t)(c0 + wv64) * 8);
    }
}

// A = W^T (m = out-feature e), B = act (n = position). Accumulators initialized from fp32 bias
// (b128 LDS broadcast): C-layout == D-layout (proven by the K-loop's C feedback in R2-R5).
// Pad rows have bias 0 + zero W rows -> acc 0 -> gelu(0)=0 keeps K-padding exact.
template<int KSTEPS, int MT>
__device__ __forceinline__ void layer_mm(const f16* __restrict__ actw, const f16* __restrict__ wb,
                                         const float* __restrict__ bl,
                                         f32x4 (&acc)[MT][2], int li, int q) {
#pragma unroll
    for (int mt = 0; mt < MT; mt++) {
        f32x4 binit = *(const f32x4*)(bl + mt * 16 + q * 4);   // same addr across li: broadcast
        acc[mt][0] = binit;
        acc[mt][1] = binit;
    }
#pragma unroll
    for (int ks = 0; ks < KSTEPS; ks++) {
        const int koff = ks * 32 + q * 8;
        f16x8 a[MT], b[2];
#pragma unroll
        for (int nt = 0; nt < 2; nt++)
            b[nt] = *(const f16x8*)(actw + (nt * 16 + li) * AST + koff);
#pragma unroll
        for (int mt = 0; mt < MT; mt++)
            a[mt] = *(const f16x8*)(wb + (mt * 16 + li) * AST + koff);
#pragma unroll
        for (int mt = 0; mt < MT; mt++)
#pragma unroll
            for (int nt = 0; nt < 2; nt++)
                acc[mt][nt] = __builtin_amdgcn_mfma_f32_16x16x32_f16(a[mt], b[nt], acc[mt][nt], 0, 0, 0);
    }
}

// C/D: col(n=pos)=lane&15, row(m=e)=(lane>>4)*4+r -> lane owns 4 consecutive features of one
// position: gelu (fp32, 4 independent chains) + pkrtz + one ds_write_b64. Bias already in acc.
template<int MT>
__device__ __forceinline__ void epilogue(f32x4 (&acc)[MT][2], f16* __restrict__ actw,
                                         int li, int q) {
#pragma unroll
    for (int mt = 0; mt < MT; mt++) {
        const int eb = mt * 16 + q * 4;
#pragma unroll
        for (int nt = 0; nt < 2; nt++) {
            union { hf16x2 h[2]; unsigned long long u; } pk;
            pk.h[0] = __builtin_amdgcn_cvt_pkrtz(gelu_f(acc[mt][nt][0]), gelu_f(acc[mt][nt][1]));
            pk.h[1] = __builtin_amdgcn_cvt_pkrtz(gelu_f(acc[mt][nt][2]), gelu_f(acc[mt][nt][3]));
            f16* dst = actw + (nt * 16 + li) * AST + eb;   // 8B aligned
            *(unsigned long long*)dst = pk.u;
        }
    }
}

// prep: fp32 w[k][d][e] -> fp16 W^T[k][e][d], zero-padded
__global__ __launch_bounds__(256) void prep_weights(
    const float* __restrict__ w0, const float* __restrict__ w1, const float* __restrict__ w2,
    const float* __restrict__ w3, const float* __restrict__ w4, f16* __restrict__ ws) {
    __shared__ f16 wl[86 * 86];
    const int k = blockIdx.x, l = blockIdx.y, tid = threadIdx.x;
    const float* wsrc;
    switch (l) { case 0: wsrc = w0; break; case 1: wsrc = w1; break; case 2: wsrc = w2; break;
                 case 3: wsrc = w3; break; default: wsrc = w4; }
    const int DI = DIv[l], DO = DOv[l], RW = WROWS[l];
    wsrc += (size_t)k * DI * DO;
    for (int i = tid; i < DI * DO; i += 256) wl[i] = (f16)wsrc[i];
    __syncthreads();
    f16* dst = ws + WOFF[l] + (size_t)k * RW * AST;
    const int tot = RW * AST;
    for (int i = tid; i < tot; i += 256) {
        int e = i / AST, d = i - e * AST;
        f16 v = (f16)0.f;
        if (e < DO && d < DI) v = wl[d * DO + e];
        dst[i] = v;
    }
}

__global__ __launch_bounds__(TPB, 3) void mlp_main(
    const float* __restrict__ x,
    const float* __restrict__ b0, const float* __restrict__ b1, const float* __restrict__ b2,
    const float* __restrict__ b3, const float* __restrict__ b4,
    const float* __restrict__ hw, const float* __restrict__ hb,
    const f16* __restrict__ ws, float* __restrict__ out) {
    extern __shared__ char smemraw[];
    f16*   act   = (f16*)smemraw;                 // [128 pos][AST]
    f16*   wbuf  = act + ACT_EL;
    float* biasl = (float*)(wbuf + WBUF_EL);      // 5 layers x 96 padded biases, fp32
    float* headl = biasl + 480;                   // 64 padded head weights, fp32

    const int tid = threadIdx.x, k = blockIdx.x, mblk = blockIdx.y;
    const int wv = tid >> 6, lane = tid & 63, li = lane & 15, q = lane >> 4;
    const int base = mblk * MTB;
    f16* actw = act + (wv * 32) * AST;            // this wave's 32 position rows

    stage_w(ws + WOFF[0] + (size_t)k * 96 * AST, wbuf, 96 * AST / 8, tid);  // async W0

    // biases (padded to 96, fp32) + head weights; overlaps with W0 staging
    for (int i = tid; i < 480; i += TPB) {
        int l = i / 96, e = i - l * 96;
        const float* bg = (l == 0) ? b0 : (l == 1) ? b1 : (l == 2) ? b2 : (l == 3) ? b3 : b4;
        int DO = (l == 0) ? 72 : (l == 1) ? 86 : (l == 2) ? 86 : (l == 3) ? 71 : 59;
        biasl[i] = (e < DO) ? bg[k * DO + e] : 0.f;
    }
    if (tid < 64) headl[tid] = (tid < 59) ? hw[tid] : 0.f;

    // layer-0 activations: act[pos][d], d = c*15+j in 0..59, cols 60..63 zero (K-pad).
    // b via threshold compare (block spans <=2 batches) — validated R5.
    {
        const int b0i = base / NOUT;
        const int thr = (b0i + 1) * NOUT;
        for (int i = tid; i < 64 * MTB; i += TPB) {
            int d = i >> 7, r = i & (MTB - 1);
            int p = base + r; if (p > NPOS - 1) p = NPOS - 1;
            int b = (p >= thr) ? b0i + 1 : b0i;
            int pos = p - b * NOUT;
            float v = 0.f;
            if (d < 60) { int c = d / 15, j = d - c * 15; v = x[(size_t)(b * C_ + c) * L_ + pos + j]; }
            act[r * AST + d] = (f16)v;
        }
    }
    const float hb0 = hb[0];
    __syncthreads();

    f32x4 acc[6][2];
    layer_mm<2, 6>(actw, wbuf, biasl + 0 * 96, acc, li, q);   // L0: K=64
    epilogue<6>(acc, actw, li, q);                            // no barrier: act rows wave-private
    __syncthreads();
    stage_w(ws + WOFF[1] + (size_t)k * 96 * AST, wbuf, 96 * AST / 8, tid);
    __syncthreads();
    layer_mm<3, 6>(actw, wbuf, biasl + 1 * 96, acc, li, q);   // L1: K=96
    epilogue<6>(acc, actw, li, q);
    __syncthreads();
    stage_w(ws + WOFF[2] + (size_t)k * 96 * AST, wbuf, 96 * AST / 8, tid);
    __syncthreads();
    layer_mm<3, 6>(actw, wbuf, biasl + 2 * 96, acc, li, q);   // L2
    epilogue<6>(acc, actw, li, q);
    __syncthreads();
    stage_w(ws + WOFF[3] + (size_t)k * 96 * AST, wbuf, 96 * AST / 8, tid);
    __syncthreads();
    layer_mm<3, 6>(actw, wbuf, biasl + 3 * 96, acc, li, q);   // L3: e>=71 -> exact 0 (L4 K-pad)
    epilogue<6>(acc, actw, li, q);
    __syncthreads();
    stage_w(ws + WOFF[4] + (size_t)k * 64 * AST, wbuf, 64 * AST / 8, tid);
    __syncthreads();

    // L4 + fused head: e 0..63 (4 m-tiles), fp32 gelu dot hw, butterfly over q
    f32x4 acc4[4][2];
    layer_mm<3, 4>(actw, wbuf, biasl + 4 * 96, acc4, li, q);
    float sum[2] = {0.f, 0.f};
#pragma unroll
    for (int mt = 0; mt < 4; mt++) {
        const int eb = mt * 16 + q * 4;
        f32x4 hh = *(const f32x4*)(headl + eb);
#pragma unroll
        for (int nt = 0; nt < 2; nt++) {
#pragma unroll
            for (int r = 0; r < 4; r++)
                sum[nt] += gelu_f(acc4[mt][nt][r]) * hh[r];
        }
    }
#pragma unroll
    for (int nt = 0; nt < 2; nt++) {
        float s = sum[nt];
        s += __shfl_xor(s, 16);
        s += __shfl_xor(s, 32);
        s += hb0;
        if (lane < 16) {
            int p = base + wv * 32 + nt * 16 + lane;
            if (p < NPOS) {
                int b = p / NOUT, pos = p - b * NOUT;
                out[((size_t)(b * K_ + k)) * NOUT + pos] = s;
            }
        }
    }
}

extern "C" void kernel_launch(void* const* d_in, const int* in_sizes, int n_in,
                              void* d_out, int out_size, void* d_ws, size_t ws_size,
                              hipStream_t stream) {
    const float* x  = (const float*)d_in[0];
    const float* w0 = (const float*)d_in[1];  const float* b0 = (const float*)d_in[2];
    const float* w1 = (const float*)d_in[3];  const float* b1 = (const float*)d_in[4];
    const float* w2 = (const float*)d_in[5];  const float* b2 = (const float*)d_in[6];
    const float* w3 = (const float*)d_in[7];  const float* b3 = (const float*)d_in[8];
    const float* w4 = (const float*)d_in[9];  const float* b4 = (const float*)d_in[10];
    const float* hw = (const float*)d_in[11]; const float* hb = (const float*)d_in[12];
    float* out = (float*)d_out;
    f16* ws = (f16*)d_ws;   // 5.96 MB

    (void)hipFuncSetAttribute((const void*)mlp_main,
                              hipFuncAttributeMaxDynamicSharedMemorySize, (int)SMEM_BYTES);

    prep_weights<<<dim3(K_, 5), 256, 0, stream>>>(w0, w1, w2, w3, w4, ws);
    mlp_main<<<dim3(K_, NBLK), TPB, SMEM_BYTES, stream>>>(x, b0, b1, b2, b3, b4, hw, hb, ws, out);
}